// Round 6
// baseline (584.745 us; speedup 1.0000x reference)
//
#include <hip/hip_runtime.h>

// Problem constants (fixed by the reference).
#define Bn    16384
#define Tn    2048
#define HIDn  5
#define NBINS 2048

static __device__ __forceinline__ float rcp_fast(float v) {
    return __builtin_amdgcn_rcpf(v);
}
static __device__ __forceinline__ float exp2_fast(float v) {
    return __builtin_amdgcn_exp2f(v);
}

// Padé(5,4) tanh, clamped to [-3.7, 3.7]. Max |err| ~1.5e-3 (incl. clamp tail).
// Numerator/denominator evaluated in parallel; one rcp on the chain.
static __device__ __forceinline__ float pade_num(float z) {      // z = x*x
    return fmaf(z, z + 105.0f, 945.0f);                          // z^2+105z+945
}
static __device__ __forceinline__ float pade_den(float z) {
    return fmaf(z, fmaf(15.0f, z, 420.0f), 945.0f);              // 15z^2+420z+945
}
static __device__ __forceinline__ float clamp37(float x) {
    return fminf(3.7f, fmaxf(-3.7f, x));
}

// Broadcast lane (8g + K) to all lanes of each 8-lane group.
// BitMode: new_src = (lane & 0x18) | K. Only executed when the whole 8-group
// shares the branch (group-uniform predicates).
template <int K>
static __device__ __forceinline__ float bcast8(float v) {
    return __int_as_float(
        __builtin_amdgcn_ds_swizzle(__float_as_int(v), (K << 5) | 0x18));
}
template <int K>
static __device__ __forceinline__ int bcast8i(int v) {
    return __builtin_amdgcn_ds_swizzle(v, (K << 5) | 0x18);
}

// ---------------------------------------------------------------------------
// Pass 1: lengths[b] = count of nonzero x[b,t]. One wave per row, float4.
// ---------------------------------------------------------------------------
__global__ __launch_bounds__(256) void len_kernel(const float* __restrict__ x,
                                                  int* __restrict__ lengths) {
    const int gtid = blockIdx.x * 256 + threadIdx.x;
    const int row  = gtid >> 6;
    const int lane = threadIdx.x & 63;
    const float4* r = reinterpret_cast<const float4*>(x + (size_t)row * Tn);
    int cnt = 0;
    #pragma unroll
    for (int i = 0; i < Tn / 4 / 64; ++i) {
        float4 v = r[i * 64 + lane];
        cnt += (v.x != 0.0f) + (v.y != 0.0f) + (v.z != 0.0f) + (v.w != 0.0f);
    }
    #pragma unroll
    for (int off = 32; off > 0; off >>= 1) cnt += __shfl_xor(cnt, off, 64);
    if (lane == 0) lengths[row] = cnt;
}

// ---------------------------------------------------------------------------
// Pass 1.5: counting sort of sequence ids by length DESCENDING -> perm[].
// ---------------------------------------------------------------------------
__global__ __launch_bounds__(1024) void sort_kernel(const int* __restrict__ lengths,
                                                    int* __restrict__ perm,
                                                    int* __restrict__ ctr) {
    __shared__ int bins[NBINS];
    __shared__ int bsum[1024];
    const int tid = threadIdx.x;
    bins[tid] = 0;
    bins[tid + 1024] = 0;
    if (tid == 0) *ctr = 0;
    __syncthreads();
    for (int i = tid; i < Bn; i += 1024) {
        int d = NBINS - lengths[i];
        d = max(0, min(NBINS - 1, d));
        atomicAdd(&bins[d], 1);
    }
    __syncthreads();
    const int a0 = bins[2 * tid], a1 = bins[2 * tid + 1];
    const int s = a0 + a1;
    bsum[tid] = s;
    __syncthreads();
    int acc = s;
    for (int off = 1; off < 1024; off <<= 1) {
        int v = (tid >= off) ? bsum[tid - off] : 0;
        __syncthreads();
        acc += v;
        bsum[tid] = acc;
        __syncthreads();
    }
    const int excl = acc - s;
    bins[2 * tid]     = excl;
    bins[2 * tid + 1] = excl + a0;
    __syncthreads();
    for (int i = tid; i < Bn; i += 1024) {
        int d = NBINS - lengths[i];
        d = max(0, min(NBINS - 1, d));
        const int p = atomicAdd(&bins[d], 1);
        perm[p] = i;
    }
}

// ---------------------------------------------------------------------------
// Pass 2: LSTM, LPT queue, 8 lanes/group, lane k = min(lsub,4) owns hidden k.
// The wall is the len-2048 critical path at SOLO latency — all effort goes
// into the serial spine: tree dot, Pade tanh (no exp on the spine), 8-step
// unroll. Gate slots: 0=i, 1=f, 2=g (RAW pre-act, Pade tanh), 3=o.
// Trans/step: 3 exp (i,f,o) + 3 rcp (r_if, r_og paired with g-den, spine).
// ---------------------------------------------------------------------------
__global__ __launch_bounds__(256, 2) void lstm_kernel(const float* __restrict__ x,
                                                      const float* __restrict__ Wih,
                                                      const float* __restrict__ Whh,
                                                      const float* __restrict__ bih,
                                                      const float* __restrict__ bhh,
                                                      const int* __restrict__ lengths,
                                                      const int* __restrict__ perm,
                                                      int* __restrict__ ctr,
                                                      float* __restrict__ out) {
    const int lsub = threadIdx.x & 7;
    const int k    = min(lsub, 4);

    const float L2E = 1.4426950408889634f;

    // Slot scales: sigma slots pre-scaled by -log2e (exp2 path); g slot raw.
    float wih[4], bias[4], whh[4][HIDn];
    #pragma unroll
    for (int j = 0; j < 4; ++j) {
        const int   gi = 5 * j + k;
        const float sj = (j == 2) ? 1.0f : -L2E;
        wih[j]  = Wih[gi] * sj;
        bias[j] = (bih[gi] + bhh[gi]) * sj;
        #pragma unroll
        for (int kk = 0; kk < HIDn; ++kk) whh[j][kk] = Whh[gi * HIDn + kk] * sj;
    }

    bool dead = false, have = false;
    int  b = 0, len = 0, t = 0;
    const float* xrow = x;
    float h0 = 0, h1 = 0, h2 = 0, h3 = 0, h4 = 0;
    float h_own = 0, c = 0;
    float4 xqA = make_float4(0.f, 0.f, 0.f, 0.f);
    float4 xqB = make_float4(0.f, 0.f, 0.f, 0.f);

    while (__any(!dead)) {
        // --- completion + refill (group-uniform) ---
        if (!dead && t >= len) {
            if (have && lsub < HIDn) out[(size_t)b * HIDn + lsub] = h_own;
            int pos = 0;
            if (lsub == 0) pos = atomicAdd(ctr, 1);
            pos = bcast8i<0>(pos);
            if (pos < Bn) {
                b    = perm[pos];
                len  = lengths[b];
                xrow = x + (size_t)b * Tn;
                t = 0; c = 0; h_own = 0;
                h0 = h1 = h2 = h3 = h4 = 0;
                xqA = *reinterpret_cast<const float4*>(xrow);
                xqB = *reinterpret_cast<const float4*>(xrow + 4);
                have = true;
            } else {
                dead = true; have = false; len = 0;
            }
        }
        // --- 8 timesteps ---
        if (!dead) {
            const float4 xnA = *reinterpret_cast<const float4*>(xrow + min(t + 8,  Tn - 8));
            const float4 xnB = *reinterpret_cast<const float4*>(xrow + min(t + 12, Tn - 4));
            const float xs[8] = { xqA.x, xqA.y, xqA.z, xqA.w,
                                  xqB.x, xqB.y, xqB.z, xqB.w };
            #pragma unroll
            for (int s = 0; s < 8; ++s) {
                if (t + s < len) {   // 8-group-uniform predicate
                    const float xv = xs[s];
                    // x-term first (independent of the h broadcast -> can
                    // issue before the swizzle wait resolves).
                    float px[4];
                    #pragma unroll
                    for (int j = 0; j < 4; ++j) px[j] = fmaf(xv, wih[j], bias[j]);
                    // Tree dot: two parallel 3-chains + join (spine ~16 cy).
                    float p[4];
                    #pragma unroll
                    for (int j = 0; j < 4; ++j) {
                        float A = fmaf(h0, whh[j][0], px[j]);
                        A = fmaf(h1, whh[j][1], A);
                        A = fmaf(h2, whh[j][2], A);
                        float B = fmaf(h4, whh[j][4], h3 * whh[j][3]);
                        p[j] = A + B;
                    }
                    // sigma gates i,f,o via exp2 (pre-scaled); g via Pade.
                    const float xi = 1.0f + exp2_fast(p[0]);
                    const float xf = 1.0f + exp2_fast(p[1]);
                    const float xo = 1.0f + exp2_fast(p[3]);
                    const float tg = clamp37(p[2]);
                    const float zg = tg * tg;
                    const float ng = pade_num(zg);
                    const float dg = pade_den(zg);
                    // Paired reciprocals: (xi*xf) and (xo*dg).
                    const float rif = rcp_fast(xi * xf);
                    const float rog = rcp_fast(xo * dg);
                    const float gi_ = xf * rif;               // sigmoid(i)
                    const float gf_ = xi * rif;               // sigmoid(f)
                    const float go_ = dg * rog;               // sigmoid(o)
                    const float gg_ = (tg * ng) * (xo * rog); // tanh(g)

                    c = fmaf(gf_, c, gi_ * gg_);              // lane-local

                    // Spine tanh(c) via Pade: clamp -> poly -> rcp -> muls.
                    const float tc = clamp37(c);
                    const float zc = tc * tc;
                    const float nc = pade_num(zc);
                    const float dc = pade_den(zc);
                    const float rc = rcp_fast(dc);
                    h_own = ((tc * nc) * go_) * rc;

                    h0 = bcast8<0>(h_own);
                    h1 = bcast8<1>(h_own);
                    h2 = bcast8<2>(h_own);
                    h3 = bcast8<3>(h_own);
                    h4 = bcast8<4>(h_own);
                }
            }
            xqA = xnA;
            xqB = xnB;
            t += 8;
        }
    }
}

extern "C" void kernel_launch(void* const* d_in, const int* in_sizes, int n_in,
                              void* d_out, int out_size, void* d_ws, size_t ws_size,
                              hipStream_t stream) {
    const float* x   = (const float*)d_in[0];  // [B,1,T,1]
    const float* Wih = (const float*)d_in[1];  // [20,1]
    const float* Whh = (const float*)d_in[2];  // [20,5]
    const float* bih = (const float*)d_in[3];  // [20]
    const float* bhh = (const float*)d_in[4];  // [20]
    float* out = (float*)d_out;                // [1,B,5]

    int* lengths = (int*)d_ws;                 // [0, Bn)
    int* perm    = lengths + Bn;               // [Bn, 2Bn)
    int* ctr     = perm + Bn;                  // one int

    len_kernel<<<Bn / 4, 256, 0, stream>>>(x, lengths);
    sort_kernel<<<1, 1024, 0, stream>>>(lengths, perm, ctr);
    lstm_kernel<<<Bn * 8 / 256, 256, 0, stream>>>(x, Wih, Whh, bih, bhh,
                                                  lengths, perm, ctr, out);
}

// Round 7
// 573.004 us; speedup vs baseline: 1.0205x; 1.0205x over previous
//
#include <hip/hip_runtime.h>

// Problem constants (fixed by the reference).
#define Bn    16384
#define Tn    2048
#define HIDn  5
#define NBINS 2048

typedef float v2f __attribute__((ext_vector_type(2)));

static __device__ __forceinline__ float rcp_fast(float v) {
    return __builtin_amdgcn_rcpf(v);
}
static __device__ __forceinline__ float med3(float x, float lo, float hi) {
    return __builtin_amdgcn_fmed3f(x, lo, hi);   // 1-op clamp
}

// Broadcast lane (8g + K) to all lanes of each 8-lane group (ds_swizzle BitMode:
// new_src = (lane & 0x18) | K).
template <int K>
static __device__ __forceinline__ float bcast8(float v) {
    return __int_as_float(
        __builtin_amdgcn_ds_swizzle(__float_as_int(v), (K << 5) | 0x18));
}

// ---------------------------------------------------------------------------
// Pass 0: zero the global histogram bins (ws is poisoned 0xAA by the harness).
// ---------------------------------------------------------------------------
__global__ void zero_kernel(int* __restrict__ gbins) {
    gbins[blockIdx.x * 256 + threadIdx.x] = 0;
}

// ---------------------------------------------------------------------------
// Pass 1: lengths[b] = count of nonzero x[b,t] (exact reference mask.sum
// semantics) + histogram of descending-key d = NBINS - len.
// One wave per row, coalesced float4.
// ---------------------------------------------------------------------------
__global__ __launch_bounds__(256) void len_kernel(const float* __restrict__ x,
                                                  int* __restrict__ lengths,
                                                  int* __restrict__ gbins) {
    const int gtid = blockIdx.x * 256 + threadIdx.x;
    const int row  = gtid >> 6;
    const int lane = threadIdx.x & 63;
    const float4* r = reinterpret_cast<const float4*>(x + (size_t)row * Tn);
    int cnt = 0;
    #pragma unroll
    for (int i = 0; i < Tn / 4 / 64; ++i) {
        float4 v = r[i * 64 + lane];
        cnt += (v.x != 0.0f) + (v.y != 0.0f) + (v.z != 0.0f) + (v.w != 0.0f);
    }
    #pragma unroll
    for (int off = 32; off > 0; off >>= 1) cnt += __shfl_xor(cnt, off, 64);
    if (lane == 0) {
        lengths[row] = cnt;
        const int d = max(0, min(NBINS - 1, NBINS - cnt));
        atomicAdd(&gbins[d], 1);
    }
}

// ---------------------------------------------------------------------------
// Pass 1.5: scan the histogram + scatter -> perm[] sorted by length DESC.
// ---------------------------------------------------------------------------
__global__ __launch_bounds__(1024) void sort_kernel(const int* __restrict__ lengths,
                                                    const int* __restrict__ gbins,
                                                    int* __restrict__ perm) {
    __shared__ int bins[NBINS];
    __shared__ int bsum[1024];
    const int tid = threadIdx.x;
    bins[tid]        = gbins[tid];
    bins[tid + 1024] = gbins[tid + 1024];
    __syncthreads();
    const int a0 = bins[2 * tid], a1 = bins[2 * tid + 1];
    const int s = a0 + a1;
    bsum[tid] = s;
    __syncthreads();
    int acc = s;
    for (int off = 1; off < 1024; off <<= 1) {
        int v = (tid >= off) ? bsum[tid - off] : 0;
        __syncthreads();
        acc += v;
        bsum[tid] = acc;
        __syncthreads();
    }
    const int excl = acc - s;
    bins[2 * tid]     = excl;
    bins[2 * tid + 1] = excl + a0;
    __syncthreads();
    for (int i = tid; i < Bn; i += 1024) {
        int d = NBINS - lengths[i];
        d = max(0, min(NBINS - 1, d));
        const int p = atomicAdd(&bins[d], 1);
        perm[p] = i;
    }
}

// ---------------------------------------------------------------------------
// Pass 2: LSTM. Static sorted assignment: group g handles perm[g] (1:1 — the
// round-5 queue degenerated to this anyway). 8 lanes/group, lane k=min(lsub,4)
// owns hidden k. Wall model: critical wave per-step = own issue + co-wave
// issue, so everything targets ISSUE:
//   - packed f32 (v_pk_fma_f32): gates paired A=(i,f), B=(g,o) as float2
//   - zero exp: all activations via Pade(7,6) tanh (clamp +-4 med3, err<=1e-3,
//     strictly <1 so no f>1 compounding); sigma = 0.5+0.5*tanh(x/2), 0.5
//     folded into weights. Trans/step: 3 rcp only.
//   - cndmask state-commit instead of exec-mask branches.
// ---------------------------------------------------------------------------
__global__ __launch_bounds__(256, 2) void lstm_kernel(const float* __restrict__ x,
                                                      const float* __restrict__ Wih,
                                                      const float* __restrict__ Whh,
                                                      const float* __restrict__ bih,
                                                      const float* __restrict__ bhh,
                                                      const int* __restrict__ lengths,
                                                      const int* __restrict__ perm,
                                                      float* __restrict__ out) {
    const int gtid = blockIdx.x * 256 + threadIdx.x;
    const int grp  = gtid >> 3;              // work-group-of-8 index = sorted rank
    const int lsub = threadIdx.x & 7;
    const int k    = min(lsub, 4);           // owned hidden index

    const int b   = perm[grp];
    const int len = lengths[b];

    // Gate rows: i=k, f=5+k, g=10+k, o=15+k. Pairs A=(i,f) scaled 0.5 (sigma
    // via tanh(x/2)), B=(g,o) scaled (1, 0.5).
    v2f wihA, wihB, bA, bB, whhA[HIDn], whhB[HIDn];
    {
        const int gi = k, gf = 5 + k, gg = 10 + k, go = 15 + k;
        wihA = (v2f){ Wih[gi] * 0.5f, Wih[gf] * 0.5f };
        wihB = (v2f){ Wih[gg],        Wih[go] * 0.5f };
        bA   = (v2f){ (bih[gi] + bhh[gi]) * 0.5f, (bih[gf] + bhh[gf]) * 0.5f };
        bB   = (v2f){ (bih[gg] + bhh[gg]),        (bih[go] + bhh[go]) * 0.5f };
        #pragma unroll
        for (int kk = 0; kk < HIDn; ++kk) {
            whhA[kk] = (v2f){ Whh[gi * HIDn + kk] * 0.5f, Whh[gf * HIDn + kk] * 0.5f };
            whhB[kk] = (v2f){ Whh[gg * HIDn + kk],        Whh[go * HIDn + kk] * 0.5f };
        }
    }

    const float* xrow = x + (size_t)b * Tn;
    float h0 = 0, h1 = 0, h2 = 0, h3 = 0, h4 = 0;
    float hq = 0, c = 0;

    float4 xq = *reinterpret_cast<const float4*>(xrow);
    for (int t = 0; __any(t < len); t += 4) {
        const float4 xn = *reinterpret_cast<const float4*>(xrow + min(t + 4, Tn - 4));
        const float xs[4] = { xq.x, xq.y, xq.z, xq.w };
        #pragma unroll
        for (int s = 0; s < 4; ++s) {
            const float xv = xs[s];
            // Packed pre-activations (6 pk_fma per pair).
            v2f pA = xv * wihA + bA;
            v2f pB = xv * wihB + bB;
            pA = h0 * whhA[0] + pA;  pB = h0 * whhB[0] + pB;
            pA = h1 * whhA[1] + pA;  pB = h1 * whhB[1] + pB;
            pA = h2 * whhA[2] + pA;  pB = h2 * whhB[2] + pB;
            pA = h3 * whhA[3] + pA;  pB = h3 * whhB[3] + pB;
            pA = h4 * whhA[4] + pA;  pB = h4 * whhB[4] + pB;
            // Pade(7,6) tanh on all four, clamp +-4 (med3).
            v2f tA, tB;
            tA.x = med3(pA.x, -4.0f, 4.0f);  tA.y = med3(pA.y, -4.0f, 4.0f);
            tB.x = med3(pB.x, -4.0f, 4.0f);  tB.y = med3(pB.y, -4.0f, 4.0f);
            const v2f zA = tA * tA, zB = tB * tB;
            const v2f nA = (zA * 21.0f + 1260.0f) * zA + 10395.0f;
            const v2f nB = (zB * 21.0f + 1260.0f) * zB + 10395.0f;
            const v2f dA = ((zA + 210.0f) * zA + 4725.0f) * zA + 10395.0f;
            const v2f dB = ((zB + 210.0f) * zB + 4725.0f) * zB + 10395.0f;
            const float rA = rcp_fast(dA.x * dA.y);
            const float rB = rcp_fast(dB.x * dB.y);
            const v2f pnA = tA * nA, pnB = tB * nB;
            const float ti = (pnA.x * dA.y) * rA;
            const float tf = (pnA.y * dA.x) * rA;
            const float tg = (pnB.x * dB.y) * rB;
            const float to = (pnB.y * dB.x) * rB;
            const float gi_ = fmaf(ti, 0.5f, 0.5f);   // sigmoid(i)
            const float gf_ = fmaf(tf, 0.5f, 0.5f);   // sigmoid(f)
            const float oo  = fmaf(to, 0.5f, 0.5f);   // sigmoid(o)

            const float cn = fmaf(gf_, c, gi_ * tg);

            // Spine tanh(c), same Pade(7,6).
            const float tc = med3(cn, -4.0f, 4.0f);
            const float zc = tc * tc;
            const float nc = fmaf(zc, fmaf(zc, 21.0f, 1260.0f), 10395.0f);
            const float dc = fmaf(zc, fmaf(zc, zc + 210.0f, 4725.0f), 10395.0f);
            const float hn = (tc * nc) * (oo * rcp_fast(dc));

            // Conditional commit (no exec-mask dance); frozen past len.
            const bool upd = (t + s) < len;
            c  = upd ? cn : c;
            hq = upd ? hn : hq;

            h0 = bcast8<0>(hq);
            h1 = bcast8<1>(hq);
            h2 = bcast8<2>(hq);
            h3 = bcast8<3>(hq);
            h4 = bcast8<4>(hq);
        }
        xq = xn;
    }

    if (lsub < HIDn) out[(size_t)b * HIDn + lsub] = hq;
}

extern "C" void kernel_launch(void* const* d_in, const int* in_sizes, int n_in,
                              void* d_out, int out_size, void* d_ws, size_t ws_size,
                              hipStream_t stream) {
    const float* x   = (const float*)d_in[0];  // [B,1,T,1]
    const float* Wih = (const float*)d_in[1];  // [20,1]
    const float* Whh = (const float*)d_in[2];  // [20,5]
    const float* bih = (const float*)d_in[3];  // [20]
    const float* bhh = (const float*)d_in[4];  // [20]
    float* out = (float*)d_out;                // [1,B,5]

    int* lengths = (int*)d_ws;                 // [0, Bn)
    int* perm    = lengths + Bn;               // [Bn, 2Bn)
    int* gbins   = perm + Bn;                  // [2Bn, 2Bn+NBINS)

    zero_kernel<<<NBINS / 256, 256, 0, stream>>>(gbins);
    len_kernel<<<Bn / 4, 256, 0, stream>>>(x, lengths, gbins);
    sort_kernel<<<1, 1024, 0, stream>>>(lengths, gbins, perm);
    lstm_kernel<<<Bn * 8 / 256, 256, 0, stream>>>(x, Wih, Whh, bih, bhh,
                                                  lengths, perm, out);
}